// Round 6
// baseline (544.509 us; speedup 1.0000x reference)
//
#include <hip/hip_runtime.h>
#include <hip/hip_bf16.h>

#define NN 512
#define CS 384
#define CZ 128
#define NH 12
#define PROJW 1152
#define FEAT 2112
#define OUTC 384

// workspace float offsets (total 3,489,792 floats = 13.96 MB)
#define WPROJ 0          // [512][1152]
#define WVT   589824     // [480][512] transposed v (rows 0-191) / vpg (rows 192-479)
#define WFEAT 835584     // [512][2112]
#define WSCR  1916928    // phase 1: bias bf16 [512*512*12] (1,572,864 float-slots); phase 2: out partials [6][512][384]

// ---------------- K1: proj GEMM + bias + fused rotation + vT scatter ----------------
__global__ __launch_bounds__(256) void proj_gemm(
    const float* __restrict__ s,
    const float* __restrict__ wq, const float* __restrict__ bq,
    const float* __restrict__ wk, const float* __restrict__ bk,
    const float* __restrict__ wv, const float* __restrict__ bv,
    const float* __restrict__ wqp, const float* __restrict__ bqp,
    const float* __restrict__ wkp, const float* __restrict__ bkp,
    const float* __restrict__ wvp, const float* __restrict__ bvp,
    const float* __restrict__ rot, const float* __restrict__ trans,
    float* __restrict__ proj, float* __restrict__ vT)
{
    __shared__ float As[32*68];
    __shared__ float Ws[32*52];
    int tid = threadIdx.x;
    int gm0 = blockIdx.x * 64;
    int gc0 = blockIdx.y * 48;
    const float *w, *b; int ldw, lc0;
    if      (gc0 < 192) { w = wq;  b = bq;  ldw = 192; lc0 = gc0;       }
    else if (gc0 < 384) { w = wk;  b = bk;  ldw = 192; lc0 = gc0 - 192; }
    else if (gc0 < 576) { w = wv;  b = bv;  ldw = 192; lc0 = gc0 - 384; }
    else if (gc0 < 720) { w = wqp; b = bqp; ldw = 144; lc0 = gc0 - 576; }
    else if (gc0 < 864) { w = wkp; b = bkp; ldw = 144; lc0 = gc0 - 720; }
    else                { w = wvp; b = bvp; ldw = 288; lc0 = gc0 - 864; }

    int mi = tid >> 4, ni = tid & 15;
    int m0 = mi * 4, n0 = ni * 3;
    float acc[4][3] = {};

    for (int k0 = 0; k0 < CS; k0 += 32) {
        for (int idx = tid; idx < 2048; idx += 256) {
            int r = idx >> 5, c = idx & 31;
            As[c*68 + r] = s[(gm0 + r)*CS + k0 + c];
        }
        for (int idx = tid; idx < 1536; idx += 256) {
            int c = idx / 48, j = idx - c*48;
            Ws[c*52 + j] = w[(k0 + c)*ldw + lc0 + j];
        }
        __syncthreads();
        #pragma unroll 8
        for (int kk = 0; kk < 32; ++kk) {
            float4 a = *(const float4*)&As[kk*68 + m0];
            float w0 = Ws[kk*52 + n0], w1 = Ws[kk*52 + n0 + 1], w2 = Ws[kk*52 + n0 + 2];
            acc[0][0] += a.x*w0; acc[0][1] += a.x*w1; acc[0][2] += a.x*w2;
            acc[1][0] += a.y*w0; acc[1][1] += a.y*w1; acc[1][2] += a.y*w2;
            acc[2][0] += a.z*w0; acc[2][1] += a.z*w1; acc[2][2] += a.z*w2;
            acc[3][0] += a.w*w0; acc[3][1] += a.w*w1; acc[3][2] += a.w*w2;
        }
        __syncthreads();
    }

    float b0 = b[lc0 + n0], b1 = b[lc0 + n0 + 1], b2 = b[lc0 + n0 + 2];
    float outv[4][3];
    if (gc0 >= 576) {
        #pragma unroll
        for (int i = 0; i < 4; ++i) {
            int gm = gm0 + m0 + i;
            const float* R = rot + gm*9;
            const float* T = trans + gm*3;
            float x = acc[i][0] + b0, y = acc[i][1] + b1, zz = acc[i][2] + b2;
            outv[i][0] = R[0]*x + R[1]*y + R[2]*zz + T[0];
            outv[i][1] = R[3]*x + R[4]*y + R[5]*zz + T[1];
            outv[i][2] = R[6]*x + R[7]*y + R[8]*zz + T[2];
        }
    } else {
        #pragma unroll
        for (int i = 0; i < 4; ++i) {
            outv[i][0] = acc[i][0] + b0; outv[i][1] = acc[i][1] + b1; outv[i][2] = acc[i][2] + b2;
        }
    }
    #pragma unroll
    for (int i = 0; i < 4; ++i) {
        float* dst = proj + (size_t)(gm0 + m0 + i)*PROJW + gc0 + n0;
        dst[0] = outv[i][0]; dst[1] = outv[i][1]; dst[2] = outv[i][2];
    }
    // transposed copies for attn phase F: v cols 384-575 -> rows 0-191; vpg cols 864-1151 -> rows 192-479
    if ((gc0 >= 384 && gc0 < 576) || gc0 >= 864) {
        int rbase = (gc0 < 576) ? (gc0 - 384) : (gc0 - 672);
        #pragma unroll
        for (int i = 0; i < 4; ++i)
            #pragma unroll
            for (int j = 0; j < 3; ++j)
                vT[(size_t)(rbase + n0 + j)*NN + gm0 + m0 + i] = outv[i][j];
    }
}

// ---------------- K2: bias GEMM: bias[nm,h] = z[nm,:]@wb[:,h] + bb[h], bf16 out ----------------
__global__ __launch_bounds__(256) void bias_gemm(
    const float* __restrict__ z, const float* __restrict__ wb,
    const float* __restrict__ bb, __hip_bfloat16* __restrict__ bias)
{
    __shared__ float s_wb[CZ*NH];
    __shared__ float s_bb[NH];
    int tid = threadIdx.x;
    for (int i = tid; i < CZ*NH; i += 256) s_wb[i] = wb[i];
    if (tid < NH) s_bb[tid] = bb[tid];
    __syncthreads();
    int wave = tid >> 6, lane = tid & 63;
    int c4 = lane & 31, rsub = lane >> 5;
    int rbase = blockIdx.x * 128;
    const float* wp = &s_wb[c4*4*12];
    for (int it = 0; it < 16; ++it) {
        int row = rbase + it*8 + wave*2 + rsub;
        float4 zv = *(const float4*)(z + (size_t)row*CZ + c4*4);
        float acc[NH];
        #pragma unroll
        for (int h = 0; h < NH; ++h)
            acc[h] = zv.x*wp[h] + zv.y*wp[12+h] + zv.z*wp[24+h] + zv.w*wp[36+h];
        #pragma unroll
        for (int off = 16; off > 0; off >>= 1) {
            #pragma unroll
            for (int h = 0; h < NH; ++h) acc[h] += __shfl_xor(acc[h], off, 64);
        }
        if ((lane & 31) == 0) {
            __hip_bfloat16* bp = bias + (size_t)row*NH;
            #pragma unroll
            for (int h = 0; h < NH; ++h) bp[h] = __float2bfloat16(acc[h] + s_bb[h]);
        }
    }
}

// ---------------- K3: attention ----------------
#define WTS 516
__global__ __launch_bounds__(256) void attn_kernel(
    const float* __restrict__ proj, const float* __restrict__ vT,
    const float* __restrict__ z, const int* __restrict__ mask,
    const unsigned short* __restrict__ bias,
    const float* __restrict__ rot, const float* __restrict__ trans,
    float* __restrict__ feat)
{
    int n = blockIdx.x, tid = threadIdx.x;
    __shared__ float s_e[NN*16];       // scores -> exp -> normalized w, [m][16]
    __shared__ float s_u[NH*WTS];      // union: s_wT (phase E/F) / s_pair 4*12*128 (phase H)
    __shared__ float s_pts[288];
    __shared__ float s_red[16*NH];
    __shared__ float s_M[NH], s_S[NH];
    float* s_wT = s_u;
    float* s_pair = s_u;

    const float* qrow  = proj + (size_t)n*PROJW;
    const float* qprow = qrow + 576;
    int mn = mask[n];

    // ---- phase A: scores (bias precomputed) ----
    for (int r = 0; r < 2; ++r) {
        int m = tid + 256*r;
        const float* krow  = proj + (size_t)m*PROJW + 192;
        const float* kprow = proj + (size_t)m*PROJW + 720;
        const unsigned* bp = (const unsigned*)(bias + (size_t)(n*NN + m)*NH);
        bool ok = (mn != 0) && (mask[m] != 0);
        float bh[12];
        #pragma unroll
        for (int j = 0; j < 6; ++j) {
            unsigned u = bp[j];
            bh[2*j]   = __uint_as_float(u << 16);
            bh[2*j+1] = __uint_as_float(u & 0xffff0000u);
        }
        float sc[12];
        #pragma unroll
        for (int h = 0; h < NH; ++h) {
            const float* qh = qrow + h*16;
            const float* kh = krow + h*16;
            float dot = 0.f;
            #pragma unroll
            for (int c4 = 0; c4 < 4; ++c4) {
                float4 kv = *(const float4*)(kh + c4*4);
                dot += qh[c4*4+0]*kv.x + qh[c4*4+1]*kv.y + qh[c4*4+2]*kv.z + qh[c4*4+3]*kv.w;
            }
            float pts = 0.f;
            const float* qph = qprow + h*12;
            const float* kph = kprow + h*12;
            #pragma unroll
            for (int j = 0; j < 12; ++j) { float d = qph[j] - kph[j]; pts += d*d; }
            float sv = dot*0.25f - 0.5f*pts + bh[h];
            sc[h] = ok ? sv : -1e30f;
        }
        float* dst = &s_e[m*16];
        *(float4*)(dst)     = make_float4(sc[0], sc[1], sc[2], sc[3]);
        *(float4*)(dst + 4) = make_float4(sc[4], sc[5], sc[6], sc[7]);
        *(float4*)(dst + 8) = make_float4(sc[8], sc[9], sc[10], sc[11]);
    }
    __syncthreads();

    // ---- phase B: max ----
    if (tid < 192) {
        int i = tid / 12, h = tid - i*12;
        float mx = -1e30f;
        for (int mm = i*32; mm < i*32 + 32; ++mm) mx = fmaxf(mx, s_e[mm*16 + h]);
        s_red[tid] = mx;
    }
    __syncthreads();
    if (tid < NH) {
        float mx = -1e30f;
        #pragma unroll
        for (int i = 0; i < 16; ++i) mx = fmaxf(mx, s_red[i*12 + tid]);
        s_M[tid] = mx;
    }
    __syncthreads();
    // ---- phase C: exp in place ----
    {
        float M[12];
        #pragma unroll
        for (int h = 0; h < NH; ++h) M[h] = s_M[h];
        for (int r = 0; r < 2; ++r) {
            int m = tid + 256*r;
            float* row = &s_e[m*16];
            float4 a = *(float4*)row, b4 = *(float4*)(row+4), c4 = *(float4*)(row+8);
            a.x = __expf(a.x - M[0]);  a.y = __expf(a.y - M[1]);
            a.z = __expf(a.z - M[2]);  a.w = __expf(a.w - M[3]);
            b4.x = __expf(b4.x - M[4]); b4.y = __expf(b4.y - M[5]);
            b4.z = __expf(b4.z - M[6]); b4.w = __expf(b4.w - M[7]);
            c4.x = __expf(c4.x - M[8]); c4.y = __expf(c4.y - M[9]);
            c4.z = __expf(c4.z - M[10]); c4.w = __expf(c4.w - M[11]);
            *(float4*)row = a; *(float4*)(row+4) = b4; *(float4*)(row+8) = c4;
        }
    }
    __syncthreads();
    // ---- phase D: sum ----
    if (tid < 192) {
        int i = tid / 12, h = tid - i*12;
        float sm = 0.f;
        for (int mm = i*32; mm < i*32 + 32; ++mm) sm += s_e[mm*16 + h];
        s_red[tid] = sm;
    }
    __syncthreads();
    if (tid < NH) {
        float sm = 0.f;
        #pragma unroll
        for (int i = 0; i < 16; ++i) sm += s_red[i*12 + tid];
        s_S[tid] = sm;
    }
    __syncthreads();
    // ---- phase E: normalize in place + transpose ----
    {
        float iS[12];
        #pragma unroll
        for (int h = 0; h < NH; ++h) iS[h] = 1.0f / s_S[h];
        for (int r = 0; r < 2; ++r) {
            int m = tid + 256*r;
            float* row = &s_e[m*16];
            float4 a = *(float4*)row, b4 = *(float4*)(row+4), c4 = *(float4*)(row+8);
            a.x *= iS[0]; a.y *= iS[1]; a.z *= iS[2]; a.w *= iS[3];
            b4.x *= iS[4]; b4.y *= iS[5]; b4.z *= iS[6]; b4.w *= iS[7];
            c4.x *= iS[8]; c4.y *= iS[9]; c4.z *= iS[10]; c4.w *= iS[11];
            *(float4*)row = a; *(float4*)(row+4) = b4; *(float4*)(row+8) = c4;
            s_wT[0*WTS + m] = a.x;  s_wT[1*WTS + m] = a.y;
            s_wT[2*WTS + m] = a.z;  s_wT[3*WTS + m] = a.w;
            s_wT[4*WTS + m] = b4.x; s_wT[5*WTS + m] = b4.y;
            s_wT[6*WTS + m] = b4.z; s_wT[7*WTS + m] = b4.w;
            s_wT[8*WTS + m] = c4.x; s_wT[9*WTS + m] = c4.y;
            s_wT[10*WTS + m] = c4.z; s_wT[11*WTS + m] = c4.w;
        }
    }
    __syncthreads();

    float* fout = feat + (size_t)n * FEAT;

    // ---- phase F: v_out scalar (192) + points (288) from vT, float4 over m ----
    for (int rnd = 0; rnd < 2; ++rnd) {
        int o = tid + rnd*256;
        if (o < 480) {
            int h = (o < 192) ? (o >> 4) : ((o - 192) / 24);
            const float* pc = vT + (size_t)o * NN;
            float acc = 0.f;
            for (int mm = 0; mm < NN; mm += 4) {
                float4 wv = *(const float4*)&s_wT[h*WTS + mm];
                float4 vv = *(const float4*)&pc[mm];
                acc += wv.x*vv.x + wv.y*vv.y + wv.z*vv.z + wv.w*vv.w;
            }
            if (o < 192) fout[h*176 + (o & 15)] = acc;
            else         s_pts[o - 192] = acc;
        }
    }
    __syncthreads();
    // ---- phase G: local transform + norms ----
    if (tid < 96) {
        int h = tid >> 3, p = tid & 7;
        const float* R = rot + n*9;
        const float* T = trans + n*3;
        float x  = s_pts[h*24 + p*3]     - T[0];
        float y  = s_pts[h*24 + p*3 + 1] - T[1];
        float zz = s_pts[h*24 + p*3 + 2] - T[2];
        float lx = R[0]*x + R[3]*y + R[6]*zz;
        float ly = R[1]*x + R[4]*y + R[7]*zz;
        float lz = R[2]*x + R[5]*y + R[8]*zz;
        float* fo = fout + h*176 + 16;
        fo[p*3] = lx; fo[p*3+1] = ly; fo[p*3+2] = lz;
        fout[h*176 + 40 + p] = sqrtf(lx*lx + ly*ly + lz*lz);
    }
    // ---- phase H: pair features, m split 4-way across waves ----
    {
        int wave = tid >> 6, lane = tid & 63;
        int mbase = wave * 128;
        const float* zr = z + ((size_t)n*NN + mbase)*CZ;
        float p0[12] = {}, p1[12] = {};
        for (int mm = 0; mm < 128; ++mm) {
            const float* wr = &s_e[(mbase + mm)*16];
            float4 a = *(const float4*)wr, b4 = *(const float4*)(wr+4), c4 = *(const float4*)(wr+8);
            float zv0 = zr[(size_t)mm*CZ + lane];
            float zv1 = zr[(size_t)mm*CZ + 64 + lane];
            p0[0] += a.x*zv0;  p0[1] += a.y*zv0;  p0[2] += a.z*zv0;  p0[3] += a.w*zv0;
            p0[4] += b4.x*zv0; p0[5] += b4.y*zv0; p0[6] += b4.z*zv0; p0[7] += b4.w*zv0;
            p0[8] += c4.x*zv0; p0[9] += c4.y*zv0; p0[10] += c4.z*zv0; p0[11] += c4.w*zv0;
            p1[0] += a.x*zv1;  p1[1] += a.y*zv1;  p1[2] += a.z*zv1;  p1[3] += a.w*zv1;
            p1[4] += b4.x*zv1; p1[5] += b4.y*zv1; p1[6] += b4.z*zv1; p1[7] += b4.w*zv1;
            p1[8] += c4.x*zv1; p1[9] += c4.y*zv1; p1[10] += c4.z*zv1; p1[11] += c4.w*zv1;
        }
        __syncthreads();   // s_wT reads (phase F) fully done before s_pair writes
        #pragma unroll
        for (int h = 0; h < NH; ++h) {
            s_pair[(wave*NH + h)*128 + lane]      = p0[h];
            s_pair[(wave*NH + h)*128 + 64 + lane] = p1[h];
        }
    }
    __syncthreads();
    {
        int c = tid & 127, jh = tid >> 7;
        #pragma unroll
        for (int j = 0; j < 6; ++j) {
            int h = jh*6 + j;
            fout[h*176 + 48 + c] = s_pair[h*128 + c] + s_pair[(NH + h)*128 + c]
                                 + s_pair[(2*NH + h)*128 + c] + s_pair[(3*NH + h)*128 + c];
        }
    }
}

// ---------------- K4: out GEMM split-K partials ----------------
__global__ __launch_bounds__(256) void out_gemm(
    const float* __restrict__ feat, const float* __restrict__ wo,
    float* __restrict__ pout)
{
    __shared__ float As[16*68];
    __shared__ float Ws[16*68];
    int tid = threadIdx.x;
    int gm0 = blockIdx.x * 64, gn0 = blockIdx.y * 64;
    int kc = blockIdx.z;
    int kbase = kc * 352;
    int mi = tid >> 4, ni = tid & 15;
    int m0 = mi * 4, n0 = ni * 4;
    float acc[4][4] = {};

    for (int kt = 0; kt < 22; ++kt) {
        int k0 = kbase + kt*16;
        for (int idx = tid; idx < 1024; idx += 256) {
            int r = idx >> 4, c = idx & 15;
            As[c*68 + r] = feat[(size_t)(gm0 + r)*FEAT + k0 + c];
        }
        for (int idx = tid; idx < 1024; idx += 256) {
            int r = idx >> 6, c = idx & 63;
            Ws[r*68 + c] = wo[(size_t)(k0 + r)*OUTC + gn0 + c];
        }
        __syncthreads();
        #pragma unroll 8
        for (int kk = 0; kk < 16; ++kk) {
            float4 a = *(const float4*)&As[kk*68 + m0];
            float4 w = *(const float4*)&Ws[kk*68 + n0];
            acc[0][0] += a.x*w.x; acc[0][1] += a.x*w.y; acc[0][2] += a.x*w.z; acc[0][3] += a.x*w.w;
            acc[1][0] += a.y*w.x; acc[1][1] += a.y*w.y; acc[1][2] += a.y*w.z; acc[1][3] += a.y*w.w;
            acc[2][0] += a.z*w.x; acc[2][1] += a.z*w.y; acc[2][2] += a.z*w.z; acc[2][3] += a.z*w.w;
            acc[3][0] += a.w*w.x; acc[3][1] += a.w*w.y; acc[3][2] += a.w*w.z; acc[3][3] += a.w*w.w;
        }
        __syncthreads();
    }
    float* pb = pout + (size_t)kc * (NN*OUTC);
    #pragma unroll
    for (int i = 0; i < 4; ++i)
        *(float4*)&pb[(size_t)(gm0 + m0 + i)*OUTC + gn0 + n0] =
            make_float4(acc[i][0], acc[i][1], acc[i][2], acc[i][3]);
}

// ---------------- K5: reduce partials + bias ----------------
__global__ __launch_bounds__(256) void out_reduce(
    const float* __restrict__ pout, const float* __restrict__ bo,
    float* __restrict__ out)
{
    int idx4 = blockIdx.x * 256 + threadIdx.x;
    int col4 = idx4 % 96;
    const float4* b4 = (const float4*)bo;
    float4 acc = b4[col4];
    #pragma unroll
    for (int kc = 0; kc < 6; ++kc) {
        float4 p = ((const float4*)(pout + (size_t)kc*(NN*OUTC)))[idx4];
        acc.x += p.x; acc.y += p.y; acc.z += p.z; acc.w += p.w;
    }
    ((float4*)out)[idx4] = acc;
}

extern "C" void kernel_launch(void* const* d_in, const int* in_sizes, int n_in,
                              void* d_out, int out_size, void* d_ws, size_t ws_size,
                              hipStream_t stream) {
    (void)in_sizes; (void)n_in; (void)out_size; (void)ws_size;
    const float* s     = (const float*)d_in[0];
    const float* z     = (const float*)d_in[1];
    const float* trans = (const float*)d_in[2];
    const float* rot   = (const float*)d_in[3];
    const int*   mask  = (const int*)d_in[4];
    const float* wq    = (const float*)d_in[5];
    const float* bq    = (const float*)d_in[6];
    const float* wk    = (const float*)d_in[7];
    const float* bk    = (const float*)d_in[8];
    const float* wv    = (const float*)d_in[9];
    const float* bv    = (const float*)d_in[10];
    const float* wqp   = (const float*)d_in[11];
    const float* bqp   = (const float*)d_in[12];
    const float* wkp   = (const float*)d_in[13];
    const float* bkp   = (const float*)d_in[14];
    const float* wvp   = (const float*)d_in[15];
    const float* bvp   = (const float*)d_in[16];
    const float* wb    = (const float*)d_in[17];
    const float* bb    = (const float*)d_in[18];
    const float* wo    = (const float*)d_in[19];
    const float* bo    = (const float*)d_in[20];
    float* ws  = (float*)d_ws;
    float* out = (float*)d_out;

    bias_gemm<<<2048, 256, 0, stream>>>(z, wb, bb, (__hip_bfloat16*)(ws + WSCR));
    proj_gemm<<<dim3(8, 24), 256, 0, stream>>>(
        s, wq, bq, wk, bk, wv, bv, wqp, bqp, wkp, bkp, wvp, bvp, rot, trans,
        ws + WPROJ, ws + WVT);
    attn_kernel<<<NN, 256, 0, stream>>>(
        ws + WPROJ, ws + WVT, z, mask, (const unsigned short*)(ws + WSCR),
        rot, trans, ws + WFEAT);
    out_gemm<<<dim3(8, 6, 6), 256, 0, stream>>>(ws + WFEAT, wo, ws + WSCR);
    out_reduce<<<192, 256, 0, stream>>>(ws + WSCR, bo, out);
}